// Round 9
// baseline (352.871 us; speedup 1.0000x reference)
//
#include <hip/hip_runtime.h>
#include <hip/hip_bf16.h>
#include <stdint.h>
#include <stddef.h>

typedef unsigned short u16;
typedef __attribute__((ext_vector_type(8))) short short8;
typedef __attribute__((ext_vector_type(4))) float f32x4;
typedef __attribute__((ext_vector_type(16))) float f32x16;

#define NB 4
#define NL 1024
#define ND 768
#define NH 12
#define NDH 64

__device__ __forceinline__ u16 f2bf(float f) {
  __hip_bfloat16 h = __float2bfloat16(f);
  return *reinterpret_cast<u16*>(&h);
}
__device__ __forceinline__ float bf2f(u16 u) {
  __hip_bfloat16 h;
  *reinterpret_cast<u16*>(&h) = u;
  return __bfloat162float(h);
}

// async global->LDS, 16B per lane. LDS dest is wave-uniform base; HW adds lane*16.
__device__ __forceinline__ void load16_to_lds(const u16* g, u16* l) {
  __builtin_amdgcn_global_load_lds(
      (__attribute__((address_space(1))) void*)(uintptr_t)g,
      (__attribute__((address_space(3))) void*)(uint32_t)(uintptr_t)l,
      16, 0, 0);
}

// ---------------- cast fp32 -> bf16 (vectorized) ----------------
__global__ __launch_bounds__(256) void cast_bf16_kernel(const float* __restrict__ in,
                                                        u16* __restrict__ out, int n4) {
  int i = blockIdx.x * 256 + threadIdx.x;
  int stride = gridDim.x * 256;
  for (; i < n4; i += stride) {
    float4 f = ((const float4*)in)[i];
    ushort4 o;
    o.x = f2bf(f.x); o.y = f2bf(f.y); o.z = f2bf(f.z); o.w = f2bf(f.w);
    ((ushort4*)out)[i] = o;
  }
}

// ---------------- transpose+cast: out[h][c][r] = in[h][r][c], 768x768 per head ----------------
__global__ __launch_bounds__(256) void transpose_cast_kernel(const float* __restrict__ in,
                                                             u16* __restrict__ out) {
  __shared__ float tile[32][33];
  int h = blockIdx.z;
  const float* src = in + (size_t)h * ND * ND;
  u16* dst = out + (size_t)h * ND * ND;
  int c0 = blockIdx.x * 32, r0 = blockIdx.y * 32;
  int tx = threadIdx.x & 31, ty = threadIdx.x >> 5;
#pragma unroll
  for (int i = 0; i < 32; i += 8)
    tile[ty + i][tx] = src[(size_t)(r0 + ty + i) * ND + c0 + tx];
  __syncthreads();
#pragma unroll
  for (int i = 0; i < 32; i += 8)
    dst[(size_t)(c0 + ty + i) * ND + r0 + tx] = f2bf(tile[tx][ty + i]);
}

// ---------------- gemm_bt: C[M,N] = A[M,K] * B[N,K]^T, bf16 in, fp32 acc ----------------
// 32x32x16 MFMA. MTILE = IM*64, NTILE = IN*64; 256 threads = 4 waves in 2x2 wave-tiles.
// BK=64 fixed. __launch_bounds__(256,4): 4 blocks/CU co-reside for barrier-drain overlap.
// Frag reads split by h (k-half): 4 ds_read_b128 then their 4 MFMAs -> halves the
// outstanding same-bank b128 burst (conflict hypothesis) and live frag registers.
// A-frag: m=lane&31, k=(lane>>5)*8+e. C/D: col=lane&31, row=(reg&3)+8*(reg>>2)+4*(lane>>5).
// XCD swizzle: chunk-contiguous work per XCD (id%8 == XCD on MI355X).
template <bool BF16_OUT, int IM, int IN, int KDIM, int LDC>
__global__ __launch_bounds__(256, 4) void gemm_bt(
    const u16* __restrict__ A, const u16* __restrict__ Bm, void* __restrict__ Cv,
    long sAb, long sAn, long sAz,
    long sBb, long sBn, long sBz,
    long sCb, long sCn, long sCz,
    int p0) {
  constexpr int BK = 64;
  constexpr int MTILE = IM * 64;
  constexpr int NTILE = IN * 64;
  constexpr int CPR = BK / 8;             // 8 chunks of 16B per row
  constexpr int ACH = MTILE * CPR / 256;
  constexpr int BCH = NTILE * CPR / 256;
  __shared__ __align__(16) u16 As[MTILE * BK];
  __shared__ __align__(16) u16 Bs[NTILE * BK];

  int id = blockIdx.x + gridDim.x * (blockIdx.y + gridDim.y * blockIdx.z);
  int total = gridDim.x * gridDim.y * gridDim.z;
  int xx, yy, zz;
  if ((total & 7) == 0) {
    int per = total >> 3;
    int wk = (id & 7) * per + (id >> 3);
    xx = wk % gridDim.x;
    int g2 = wk / gridDim.x;
    yy = g2 % gridDim.y;
    zz = g2 / gridDim.y;
  } else {
    xx = blockIdx.x; yy = blockIdx.y; zz = blockIdx.z;
  }

  int g = p0 + zz;
  int b = g / NH, n = g % NH;
  A  += (size_t)b * sAb + (size_t)n * sAn + (size_t)zz * sAz;
  Bm += (size_t)b * sBb + (size_t)n * sBn + (size_t)zz * sBz;
  size_t cOff = (size_t)b * sCb + (size_t)n * sCn + (size_t)zz * sCz;

  int m0 = yy * MTILE, n0 = xx * NTILE;
  int t = threadIdx.x;
  int lane = t & 63, w = t >> 6;
  int m32 = lane & 31, kg = lane >> 5;
  int wm = w >> 1, wn = w & 1;

  // single staging base per matrix (XOR swizzle; u-offsets are compile-time)
  const u16* gAb;
  const u16* gBb;
  {
    int r = t / CPR;
    int cc = (t & (CPR - 1)) ^ (r & 7);
    gAb = A + (size_t)(m0 + r) * KDIM + cc * 8;
    gBb = Bm + (size_t)(n0 + r) * KDIM + cc * 8;
  }

  f32x16 acc[IM][IN];
#pragma unroll
  for (int i = 0; i < IM; i++)
#pragma unroll
    for (int j = 0; j < IN; j++)
#pragma unroll
      for (int r = 0; r < 16; r++) acc[i][j][r] = 0.f;

#pragma unroll 1
  for (int k0 = 0; k0 < KDIM; k0 += BK) {
    __syncthreads();
#pragma unroll
    for (int u = 0; u < ACH; u++)
      load16_to_lds(gAb + (size_t)u * 32 * KDIM, &As[(size_t)(u * 256 + w * 64) * 8]);
    gAb += BK;
#pragma unroll
    for (int u = 0; u < BCH; u++)
      load16_to_lds(gBb + (size_t)u * 32 * KDIM, &Bs[(size_t)(u * 256 + w * 64) * 8]);
    gBb += BK;
    __syncthreads();

#pragma unroll
    for (int kc = 0; kc < 2; kc++) {
#pragma unroll
      for (int h = 0; h < 2; h++) {
        short8 af[IM], bfr[IN];
#pragma unroll
        for (int i = 0; i < IM; i++) {
          int row = wm * (IM * 32) + i * 32 + m32;
          int ck = (kc * 4 + h * 2 + kg) ^ (row & 7);
          af[i] = *(const short8*)&As[row * BK + ck * 8];
        }
#pragma unroll
        for (int j = 0; j < IN; j++) {
          int row = wn * (IN * 32) + j * 32 + m32;
          int ck = (kc * 4 + h * 2 + kg) ^ (row & 7);
          bfr[j] = *(const short8*)&Bs[row * BK + ck * 8];
        }
#pragma unroll
        for (int i = 0; i < IM; i++)
#pragma unroll
          for (int j = 0; j < IN; j++)
            acc[i][j] = __builtin_amdgcn_mfma_f32_32x32x16_bf16(af[i], bfr[j], acc[i][j], 0, 0, 0);
      }
    }
  }

  // epilogue: row = (reg&3) + 8*(reg>>2) + 4*kg; col = m32 (within 32x32 tile)
#pragma unroll
  for (int i = 0; i < IM; i++) {
#pragma unroll
    for (int j = 0; j < IN; j++) {
      int colg = n0 + wn * (IN * 32) + j * 32 + m32;
#pragma unroll
      for (int r = 0; r < 16; r++) {
        int rowg = m0 + wm * (IM * 32) + i * 32 + (r & 3) + 8 * (r >> 2) + 4 * kg;
        float vv = acc[i][j][r];
        if (BF16_OUT) {
          ((u16*)Cv)[cOff + (size_t)rowg * LDC + colg] = f2bf(vv);
        } else {
          ((float*)Cv)[cOff + (size_t)rowg * LDC + colg] = vv;
        }
      }
    }
  }
}

// ---------------- fused softmax + PV ----------------
// out[b][l][n*64+dh] = sum_m exp(Sb[z][l][m]) * V2[z][dh][m] / sum_m exp(Sb[z][l][m])
// Logits are O(1) (bf16-safe) -> no max subtraction, single pass, no rescale.
// 64-row tiles, grid (16,c). S staged in LDS (16 KB); V2 B-frags loaded DIRECTLY from
// global (16B contiguous, L2-resident per-z slice on one XCD via the z-contiguous
// swizzle) -> no Vs stage, one barrier fewer per m-tile, ~6 blocks/CU of latency hiding.
// 5th B-tile (ones in col 0) makes the MFMA compute row sums; epilogue divides.
__global__ __launch_bounds__(256, 6) void softmax_pv_kernel(
    const u16* __restrict__ Sb, const u16* __restrict__ V2, float* __restrict__ out,
    int p0) {
  __shared__ __align__(16) u16 Ps[64 * 128];  // 16 KB

  int id = blockIdx.x + gridDim.x * blockIdx.y;
  int total = gridDim.x * gridDim.y;
  int xx, zz;
  if ((total & 7) == 0) {
    int per = total >> 3;
    int wk = (id & 7) * per + (id >> 3);
    xx = wk & 15; zz = wk >> 4;
  } else {
    xx = blockIdx.x; zz = blockIdx.y;
  }

  int g = p0 + zz;
  int b = g / NH, n = g % NH;
  const u16* S = Sb + (size_t)zz * NL * NL;
  const u16* V = V2 + (size_t)zz * NDH * NL;

  int l0 = xx * 64;
  int t = threadIdx.x;
  int lane = t & 63, w = t >> 6;
  int row16 = lane & 15, q = lane >> 4;
  int rs = row16 & 7;

  f32x4 acc[5];
#pragma unroll
  for (int j = 0; j < 5; j++) acc[j] = (f32x4){0.f, 0.f, 0.f, 0.f};

  short8 onesf;
  {
    short val = (row16 == 0) ? (short)0x3F80 : (short)0;
#pragma unroll
    for (int e = 0; e < 8; e++) onesf[e] = val;
  }

  // S staging bases (write-side swizzle cc = (c&15)^(r&7))
  const u16* ssrc[4];
#pragma unroll
  for (int u = 0; u < 4; u++) {
    int c = u * 256 + t;
    int r = c >> 4, cc = (c & 15) ^ (r & 7);
    ssrc[u] = S + (size_t)(l0 + r) * NL + cc * 8;
  }
  // direct V2 fragment pointers: frag j at (dh = j*16+row16, m = mo + kk*32 + q*8)
  const u16* vp[4];
#pragma unroll
  for (int j = 0; j < 4; j++)
    vp[j] = V + (size_t)(j * 16 + row16) * NL + q * 8;

#pragma unroll 1
  for (int mt = 0; mt < 8; mt++) {
    int mo = mt * 128;
    __syncthreads();
#pragma unroll
    for (int u = 0; u < 4; u++)
      load16_to_lds(ssrc[u] + mo, &Ps[(size_t)(u * 256 + w * 64) * 8]);
    __syncthreads();

#pragma unroll
    for (int kk = 0; kk < 4; kk++) {
      short8 bfr[4];
#pragma unroll
      for (int j = 0; j < 4; j++)
        bfr[j] = *(const short8*)(vp[j] + mo + kk * 32);
      int ch = ((kk * 4 + q) ^ rs) * 16;  // byte offset within 256B row
      int lrow = w * 16 + row16;
      short8 raw = *(const short8*)((const char*)Ps + lrow * 256 + ch);
      short8 af;
#pragma unroll
      for (int e = 0; e < 8; e++) af[e] = (short)f2bf(__expf(bf2f((u16)raw[e])));
#pragma unroll
      for (int j = 0; j < 4; j++)
        acc[j] = __builtin_amdgcn_mfma_f32_16x16x32_bf16(af, bfr[j], acc[j], 0, 0, 0);
      acc[4] = __builtin_amdgcn_mfma_f32_16x16x32_bf16(af, onesf, acc[4], 0, 0, 0);
    }
  }

  // epilogue: row = l0 + w*16 + q*4 + r; col(dh) = j*16 + row16
#pragma unroll
  for (int r = 0; r < 4; r++) {
    float sum = __shfl(acc[4][r], lane & 48, 64);
    float inv = 1.0f / sum;
    int row = l0 + w * 16 + q * 4 + r;
    float* op = out + ((size_t)b * NL + row) * ND + n * NDH;
#pragma unroll
    for (int j = 0; j < 4; j++)
      op[j * 16 + row16] = acc[j][r] * inv;
  }
}

extern "C" void kernel_launch(void* const* d_in, const int* in_sizes, int n_in,
                              void* d_out, int out_size, void* d_ws, size_t ws_size,
                              hipStream_t stream) {
  (void)in_sizes; (void)n_in; (void)out_size;
  const float* x  = (const float*)d_in[0];
  const float* kI = (const float*)d_in[1];
  const float* qI = (const float*)d_in[2];
  const float* vI = (const float*)d_in[3];
  float* out = (float*)d_out;

  size_t off = 0;
  char* wsb = (char*)d_ws;
  auto alloc = [&](size_t bytes) -> char* {
    char* p = wsb + off;
    off += (bytes + 255) & ~(size_t)255;
    return p;
  };
  u16* xb = (u16*)alloc((size_t)NB * NL * ND * 2);   // bf16 x, [b][l][d]
  u16* qT = (u16*)alloc((size_t)NH * ND * ND * 2);   // q^T per head: [n][d][c]
  u16* kT = (u16*)alloc((size_t)NH * ND * ND * 2);   // k^T per head: [n][e][c]
  u16* vb = (u16*)alloc((size_t)NH * NDH * ND * 2);  // bf16 v, [n][dh][d]
  u16* MT = (u16*)alloc((size_t)NH * ND * ND * 2);   // MT[n][e][d] = M[d][e]
  size_t fixedSz = off;
  const size_t perPair = (size_t)NL * ND * 2 + (size_t)NL * NL * 2 + (size_t)NDH * NL * 2;
  int chunk = NB * NH;
  if (fixedSz + (size_t)chunk * perPair > ws_size) {
    size_t avail = ws_size > fixedSz ? ws_size - fixedSz : 0;
    chunk = (int)(avail / perPair);
    if (chunk < 1) chunk = 1;
    if (chunk > NB * NH) chunk = NB * NH;
  }
  u16* T  = (u16*)alloc((size_t)chunk * NL * ND * 2);   // [z][l][e]
  u16* Sb = (u16*)alloc((size_t)chunk * NL * NL * 2);   // [z][l][m] logits
  u16* V2 = (u16*)alloc((size_t)chunk * NDH * NL * 2);  // [z][dh][m]

  const long DD  = (long)ND * ND;
  const long LD  = (long)NL * ND;
  const long LL  = (long)NL * NL;
  const long DHD = (long)NDH * ND;
  const long DHL = (long)NDH * NL;

  {
    int n4 = NB * NL * ND / 4;
    cast_bf16_kernel<<<dim3((n4 + 255) / 256), dim3(256), 0, stream>>>(x, xb, n4);
    int n4v = NH * NDH * ND / 4;
    cast_bf16_kernel<<<dim3((n4v + 255) / 256), dim3(256), 0, stream>>>(vI, vb, n4v);
  }
  transpose_cast_kernel<<<dim3(24, 24, NH), dim3(256), 0, stream>>>(qI, qT);
  transpose_cast_kernel<<<dim3(24, 24, NH), dim3(256), 0, stream>>>(kI, kT);

  // MT[n][e][d] = sum_c kT[n][e][c] * qT[n][d][c]   (768x768, K=768)
  gemm_bt<true, 2, 2, 768, ND><<<dim3(6, 6, NH), dim3(256), 0, stream>>>(
      kT, qT, MT,
      0, DD, 0,  0, DD, 0,  0, DD, 0, 0);

  for (int p0 = 0; p0 < NB * NH; p0 += chunk) {
    int c = NB * NH - p0;
    if (c > chunk) c = chunk;
    // V2[z][dh][m] = sum_d vb[n][dh][d] * xb[b][m][d]   (64x1024, K=768), 64x64 tiles
    gemm_bt<true, 1, 1, 768, NL><<<dim3(16, 1, c), dim3(256), 0, stream>>>(
        vb, xb, V2,
        0, DHD, 0,  LD, 0, 0,  0, 0, DHL, p0);
    // T[z][l][e] = sum_d xb[b][l][d] * MT[n][e][d]   (1024x768, K=768)
    gemm_bt<true, 2, 2, 768, ND><<<dim3(6, 8, c), dim3(256), 0, stream>>>(
        xb, MT, T,
        LD, 0, 0,  0, DD, 0,  0, 0, LD, p0);
    // Sb[z][l][m] = sum_e T[z][l][e] * xb[b][m][e]   (1024x1024, K=768)
    gemm_bt<true, 2, 2, 768, NL><<<dim3(8, 8, c), dim3(256), 0, stream>>>(
        T, xb, Sb,
        0, 0, LD,  LD, 0, 0,  0, 0, LL, p0);
    // fused softmax + PV -> writes out directly
    softmax_pv_kernel<<<dim3(16, c), dim3(256), 0, stream>>>(Sb, V2, out, p0);
  }
}